// Round 1
// baseline (448.560 us; speedup 1.0000x reference)
//
#include <hip/hip_runtime.h>

// SEST: SE-gating + soft-threshold, fused single pass.
// inputs [B,F,E] f32, W1[F,R] W2[R,F] W3[F,R] W4[R,F], out [B,F,2E] f32.
// B=16384 F=39 E=64 R=13. Memory-bound: 491 MB total -> ~78us floor @6.3TB/s.

#define SEST_B 16384
#define SEST_F 39
#define SEST_E 64
#define SEST_R 13

__global__ __launch_bounds__(256) void sest_kernel(
    const float* __restrict__ x,
    const float* __restrict__ W1,
    const float* __restrict__ W2,
    const float* __restrict__ W3,
    const float* __restrict__ W4,
    float* __restrict__ out)
{
    const int b    = blockIdx.x;
    const int tid  = threadIdx.x;
    const int w    = tid >> 6;      // wave 0..3
    const int lane = tid & 63;
    const int g    = lane >> 4;     // 16-lane group 0..3 (one f-row each)
    const int s    = lane & 15;     // float4 slot within row (16*4 = 64 = E)

    __shared__ float Zm[SEST_F];    // mean
    __shared__ float Am[SEST_F];    // abs-mean
    __shared__ float H1[SEST_R];
    __shared__ float H2[SEST_R];
    __shared__ float A2s[SEST_F];   // gate
    __shared__ float Th[SEST_F];    // threshold

    const float4* in4 = reinterpret_cast<const float4*>(x)
                        + (size_t)b * SEST_F * (SEST_E / 4);

    // ---- phase 1: vector load (kept in regs) + per-row sum / abs-sum ----
    float4 xr[3];
    #pragma unroll
    for (int i = 0; i < 3; ++i) {
        const int f = i * 16 + w * 4 + g;   // covers 0..47, predicate f<39
        float sx = 0.f, sa = 0.f;
        if (f < SEST_F) {
            float4 v = in4[f * (SEST_E / 4) + s];
            xr[i] = v;
            sx = v.x + v.y + v.z + v.w;
            sa = fabsf(v.x) + fabsf(v.y) + fabsf(v.z) + fabsf(v.w);
        }
        // reduce across the 16 lanes of this group (masks<16 stay in group)
        #pragma unroll
        for (int m = 1; m < 16; m <<= 1) {
            sx += __shfl_xor(sx, m);
            sa += __shfl_xor(sa, m);
        }
        if (f < SEST_F && s == 0) {
            Zm[f] = sx * (1.0f / 64.0f);
            Am[f] = sa * (1.0f / 64.0f);
        }
    }
    __syncthreads();

    // ---- phase 2a: hidden layers (wave0 = gate branch, wave1 = thres) ----
    if (tid < SEST_R) {
        float acc = 0.f;
        #pragma unroll
        for (int f = 0; f < SEST_F; ++f) acc += Zm[f] * W1[f * SEST_R + tid];
        H1[tid] = fmaxf(acc, 0.f);
    } else if (tid >= 64 && tid < 64 + SEST_R) {
        const int r = tid - 64;
        float acc = 0.f;
        #pragma unroll
        for (int f = 0; f < SEST_F; ++f) acc += Am[f] * W3[f * SEST_R + r];
        H2[r] = fmaxf(acc, 0.f);
    }
    __syncthreads();

    // ---- phase 2b: output layers ----
    if (tid < SEST_F) {
        float acc = 0.f;
        #pragma unroll
        for (int r = 0; r < SEST_R; ++r) acc += H1[r] * W2[r * SEST_F + tid];
        A2s[tid] = fmaxf(acc, 0.f);
    } else if (tid >= 64 && tid < 64 + SEST_F) {
        const int f = tid - 64;
        float acc = 0.f;
        #pragma unroll
        for (int r = 0; r < SEST_R; ++r) acc += H2[r] * W4[r * SEST_F + f];
        Th[f] = Am[f] * fmaxf(acc, 0.f);   // thres = abs_mean * relu(...)
    }
    __syncthreads();

    // ---- phase 3: V = x*gate ; R = sign(x)*max(|x|-thres,0) ----
    float4* out4 = reinterpret_cast<float4*>(out)
                   + (size_t)b * SEST_F * (2 * SEST_E / 4);
    #pragma unroll
    for (int i = 0; i < 3; ++i) {
        const int f = i * 16 + w * 4 + g;
        if (f < SEST_F) {
            const float a2 = A2s[f];
            const float th = Th[f];
            const float4 v = xr[i];
            float4 V, R;
            V.x = v.x * a2; V.y = v.y * a2; V.z = v.z * a2; V.w = v.w * a2;
            R.x = copysignf(fmaxf(fabsf(v.x) - th, 0.f), v.x);
            R.y = copysignf(fmaxf(fabsf(v.y) - th, 0.f), v.y);
            R.z = copysignf(fmaxf(fabsf(v.z) - th, 0.f), v.z);
            R.w = copysignf(fmaxf(fabsf(v.w) - th, 0.f), v.w);
            // row f of out = [V(64) | R(64)] = 32 float4
            out4[f * 32 + s]      = V;
            out4[f * 32 + 16 + s] = R;
        }
    }
}

extern "C" void kernel_launch(void* const* d_in, const int* in_sizes, int n_in,
                              void* d_out, int out_size, void* d_ws, size_t ws_size,
                              hipStream_t stream) {
    const float* x  = (const float*)d_in[0];
    const float* W1 = (const float*)d_in[1];
    const float* W2 = (const float*)d_in[2];
    const float* W3 = (const float*)d_in[3];
    const float* W4 = (const float*)d_in[4];
    float* out = (float*)d_out;

    sest_kernel<<<SEST_B, 256, 0, stream>>>(x, W1, W2, W3, W4, out);
}